// Round 1
// baseline (36986.365 us; speedup 1.0000x reference)
//
#include <hip/hip_runtime.h>

// GRU 2-layer, B=64, S=1024, I=256, H=512, O=512.
// Round 1: correctness-first multi-launch design.
//   - all matmuls in bf16 MFMA (16x16x32), fp32 accumulate
//   - hidden state carried in fp32 (gate math), bf16 copy for matmul inputs
//   - 2 cell launches per timestep (layer0, layer1), ping-pong state slots
//   - Y (layer-1 outputs) staged bf16 in ws; final FC = tiled MFMA GEMM w/ bias
// Known bottleneck (accepted this round): 2048 sequential small launches.

typedef unsigned short u16;
typedef __attribute__((ext_vector_type(8))) short bf16x8;
typedef __attribute__((ext_vector_type(4))) float f32x4;

#define B_ 64
#define S_ 1024
#define I_ 256
#define H_ 512
#define O_ 512
#define G3 1536  // 3*H

__device__ __forceinline__ u16 f2bf(float f) {
  union { float f; unsigned u; } v; v.f = f;
  unsigned r = v.u + 0x7fffu + ((v.u >> 16) & 1u);  // RNE
  return (u16)(r >> 16);
}

__device__ __forceinline__ float sigmoidf_(float x) {
  return 1.0f / (1.0f + __expf(-x));
}

// ---------------- fp32 -> bf16 bulk convert ----------------
__global__ void conv_bf16(const float* __restrict__ src, u16* __restrict__ dst, int n4) {
  int i = blockIdx.x * blockDim.x + threadIdx.x;
  int stride = gridDim.x * blockDim.x;
  for (; i < n4; i += stride) {
    float4 v = ((const float4*)src)[i];
    ushort4 o;
    o.x = f2bf(v.x); o.y = f2bf(v.y); o.z = f2bf(v.z); o.w = f2bf(v.w);
    ((ushort4*)dst)[i] = o;
  }
}

// ---------------- GRU cell ----------------
// Computes h_new = GRUCell(x, h_prev) for 64 batches x 512 units.
// Grid: 32 blocks (16 units each), 256 threads (4 waves = 4 batch-tiles of 16).
// Gates: W rows [0:512)=r, [512:1024)=z, [1024:1536)=n (torch order).
__global__ __launch_bounds__(256) void gru_cell(
    const u16* __restrict__ Ax, long axStride, int Kx,   // x input [64 x Kx] bf16, row stride
    const u16* __restrict__ Wih,                          // [1536 x Kx] bf16 row-major
    const u16* __restrict__ Whh,                          // [1536 x 512] bf16 row-major
    const u16* __restrict__ Hprev_bf,                     // [64 x 512] bf16
    const float* __restrict__ Hprev_f,                    // [64 x 512] f32
    const float* __restrict__ bih, const float* __restrict__ bhh,  // [1536] f32
    float* __restrict__ Hnew_f, u16* __restrict__ Hnew_bf,
    u16* __restrict__ Yout, long yStride)                 // optional bf16 copy (layer 1)
{
  const int wave = threadIdx.x >> 6;
  const int lane = threadIdx.x & 63;
  const int m0 = wave * 16;            // batch-row tile base
  const int n0 = blockIdx.x * 16;      // hidden-unit tile base
  const int lm = lane & 15;
  const int quad = lane >> 4;

  f32x4 accr = {0.f, 0.f, 0.f, 0.f};
  f32x4 accz = {0.f, 0.f, 0.f, 0.f};
  f32x4 accni = {0.f, 0.f, 0.f, 0.f};   // x-part of n gate
  f32x4 accnh = {0.f, 0.f, 0.f, 0.f};   // h-part of n gate

  // ---- x contribution: gi = x @ Wih^T ----
  {
    const u16* a_base = Ax + (size_t)(m0 + lm) * axStride + quad * 8;
    const u16* wr = Wih + (size_t)(n0 + lm) * Kx + quad * 8;
    const u16* wz = wr + (size_t)512 * Kx;
    const u16* wn = wr + (size_t)1024 * Kx;
    for (int ks = 0; ks < Kx; ks += 32) {
      bf16x8 a  = *(const bf16x8*)(a_base + ks);
      bf16x8 br = *(const bf16x8*)(wr + ks);
      bf16x8 bz = *(const bf16x8*)(wz + ks);
      bf16x8 bn = *(const bf16x8*)(wn + ks);
      accr  = __builtin_amdgcn_mfma_f32_16x16x32_bf16(a, br, accr, 0, 0, 0);
      accz  = __builtin_amdgcn_mfma_f32_16x16x32_bf16(a, bz, accz, 0, 0, 0);
      accni = __builtin_amdgcn_mfma_f32_16x16x32_bf16(a, bn, accni, 0, 0, 0);
    }
  }
  // ---- h contribution: gh = h @ Whh^T ----
  {
    const u16* a_base = Hprev_bf + (size_t)(m0 + lm) * H_ + quad * 8;
    const u16* wr = Whh + (size_t)(n0 + lm) * H_ + quad * 8;
    const u16* wz = wr + (size_t)512 * H_;
    const u16* wn = wr + (size_t)1024 * H_;
    for (int ks = 0; ks < H_; ks += 32) {
      bf16x8 a  = *(const bf16x8*)(a_base + ks);
      bf16x8 br = *(const bf16x8*)(wr + ks);
      bf16x8 bz = *(const bf16x8*)(wz + ks);
      bf16x8 bn = *(const bf16x8*)(wn + ks);
      accr  = __builtin_amdgcn_mfma_f32_16x16x32_bf16(a, br, accr, 0, 0, 0);
      accz  = __builtin_amdgcn_mfma_f32_16x16x32_bf16(a, bz, accz, 0, 0, 0);
      accnh = __builtin_amdgcn_mfma_f32_16x16x32_bf16(a, bn, accnh, 0, 0, 0);
    }
  }

  // ---- gates + state update ----
  const int n = n0 + lm;                       // C/D col = lane&15
  const float br_ = bih[n] + bhh[n];
  const float bz_ = bih[512 + n] + bhh[512 + n];
  const float bni = bih[1024 + n];
  const float bnh = bhh[1024 + n];
  #pragma unroll
  for (int i = 0; i < 4; ++i) {
    const int m = m0 + quad * 4 + i;           // C/D row = quad*4 + reg
    float r  = sigmoidf_(accr[i] + br_);
    float z  = sigmoidf_(accz[i] + bz_);
    float nn = tanhf(accni[i] + bni + r * (accnh[i] + bnh));
    float hp = Hprev_f[(size_t)m * H_ + n];
    float hn = (1.0f - z) * nn + z * hp;
    Hnew_f[(size_t)m * H_ + n] = hn;
    u16 hb = f2bf(hn);
    Hnew_bf[(size_t)m * H_ + n] = hb;
    if (Yout) Yout[(size_t)m * yStride + n] = hb;
  }
}

// ---------------- final FC: C[65536,512] = Y_bf16 @ Wfc^T + b ----------------
// 128x128 block tile, 2x2 waves, each wave 64x64 via 4x4 MFMA tiles. No LDS:
// fragments straight from global (W L2-resident, Y rows reused via L2).
__global__ __launch_bounds__(256) void fc_gemm(
    const u16* __restrict__ A,   // [65536 x 512] bf16
    const u16* __restrict__ Bm,  // [512 x 512] bf16 (Wfc row-major = B^T)
    const float* __restrict__ bias,
    float* __restrict__ C)
{
  const int bid = blockIdx.x;
  const int bm = bid >> 2, bn = bid & 3;
  const int wave = threadIdx.x >> 6, lane = threadIdx.x & 63;
  const int wm = wave >> 1, wn = wave & 1;
  const int M0 = bm * 128 + wm * 64;
  const int N0 = bn * 128 + wn * 64;
  const int lm = lane & 15, quad = lane >> 4;

  f32x4 acc[4][4];
  #pragma unroll
  for (int j = 0; j < 4; ++j) {
    float bv = bias[N0 + j * 16 + lm];
    #pragma unroll
    for (int i = 0; i < 4; ++i) acc[i][j] = (f32x4){bv, bv, bv, bv};
  }

  const u16* a0 = A + (size_t)(M0 + lm) * 512 + quad * 8;
  const u16* b0 = Bm + (size_t)(N0 + lm) * 512 + quad * 8;
  for (int ks = 0; ks < 512; ks += 32) {
    bf16x8 af[4], bfr[4];
    #pragma unroll
    for (int i = 0; i < 4; ++i) af[i]  = *(const bf16x8*)(a0 + (size_t)i * 16 * 512 + ks);
    #pragma unroll
    for (int j = 0; j < 4; ++j) bfr[j] = *(const bf16x8*)(b0 + (size_t)j * 16 * 512 + ks);
    #pragma unroll
    for (int i = 0; i < 4; ++i)
      #pragma unroll
      for (int j = 0; j < 4; ++j)
        acc[i][j] = __builtin_amdgcn_mfma_f32_16x16x32_bf16(af[i], bfr[j], acc[i][j], 0, 0, 0);
  }

  #pragma unroll
  for (int i = 0; i < 4; ++i)
    #pragma unroll
    for (int j = 0; j < 4; ++j)
      #pragma unroll
      for (int r = 0; r < 4; ++r) {
        const int m = M0 + i * 16 + quad * 4 + r;
        const int n = N0 + j * 16 + lm;
        C[(size_t)m * 512 + n] = acc[i][j][r];
      }
}

// ---------------- final hidden copy ----------------
__global__ void copy_hidden(const float* __restrict__ h0, const float* __restrict__ h1,
                            float* __restrict__ out) {
  int i = blockIdx.x * 256 + threadIdx.x;  // grid 128 blocks x 256 = 32768
  out[i] = h0[i];
  out[32768 + i] = h1[i];
}

// ---------------- host ----------------
extern "C" void kernel_launch(void* const* d_in, const int* in_sizes, int n_in,
                              void* d_out, int out_size, void* d_ws, size_t ws_size,
                              hipStream_t stream) {
  const float* x     = (const float*)d_in[0];
  const float* W_ih0 = (const float*)d_in[1];
  const float* W_hh0 = (const float*)d_in[2];
  const float* b_ih0 = (const float*)d_in[3];
  const float* b_hh0 = (const float*)d_in[4];
  const float* W_ih1 = (const float*)d_in[5];
  const float* W_hh1 = (const float*)d_in[6];
  const float* b_ih1 = (const float*)d_in[7];
  const float* b_hh1 = (const float*)d_in[8];
  const float* W_fc  = (const float*)d_in[9];
  const float* b_fc  = (const float*)d_in[10];
  float* out = (float*)d_out;

  char* ws = (char*)d_ws;
  // ws layout (bytes)
  const size_t OFF_XBF  = 0;                     // 64*1024*256 bf16 = 33,554,432
  const size_t OFF_YBF  = 33554432;              // 64*1024*512 bf16 = 67,108,864
  const size_t OFF_WIH0 = 100663296;             // 1536*256  bf16
  const size_t OFF_WHH0 = 101449728;             // 1536*512  bf16
  const size_t OFF_WIH1 = 103022592;             // 1536*512  bf16
  const size_t OFF_WHH1 = 104595456;             // 1536*512  bf16
  const size_t OFF_WFC  = 106168320;             // 512*512   bf16
  const size_t OFF_H0F  = 106692608;             // 2 slots * 64*512 f32
  const size_t OFF_H1F  = OFF_H0F + 262144;
  const size_t OFF_H0B  = OFF_H1F + 262144;      // 2 slots * 64*512 bf16
  const size_t OFF_H1B  = OFF_H0B + 131072;
  // total ~107.5 MB

  u16* x_bf    = (u16*)(ws + OFF_XBF);
  u16* y_bf    = (u16*)(ws + OFF_YBF);
  u16* wih0_bf = (u16*)(ws + OFF_WIH0);
  u16* whh0_bf = (u16*)(ws + OFF_WHH0);
  u16* wih1_bf = (u16*)(ws + OFF_WIH1);
  u16* whh1_bf = (u16*)(ws + OFF_WHH1);
  u16* wfc_bf  = (u16*)(ws + OFF_WFC);
  float* h0f   = (float*)(ws + OFF_H0F);
  float* h1f   = (float*)(ws + OFF_H1F);
  u16*   h0b   = (u16*)(ws + OFF_H0B);
  u16*   h1b   = (u16*)(ws + OFF_H1B);

  const int HSZ = B_ * H_;  // 32768 elems per state slot

  // zero both ping-pong state regions (slot 0 is read at t=0)
  hipMemsetAsync(ws + OFF_H0F, 0, 262144 * 2 + 131072 * 2, stream);

  // fp32 -> bf16 conversions (redone every call; ws is re-poisoned by harness)
  auto conv = [&](const float* s, u16* d, int n) {
    int n4 = n / 4;
    int blocks = (n4 + 255) / 256; if (blocks > 4096) blocks = 4096;
    conv_bf16<<<blocks, 256, 0, stream>>>(s, d, n4);
  };
  conv(x,     x_bf,    B_ * S_ * I_);
  conv(W_ih0, wih0_bf, G3 * I_);
  conv(W_hh0, whh0_bf, G3 * H_);
  conv(W_ih1, wih1_bf, G3 * H_);
  conv(W_hh1, whh1_bf, G3 * H_);
  conv(W_fc,  wfc_bf,  O_ * H_);

  // sequential recurrence: 2 cell launches per timestep
  for (int t = 0; t < S_; ++t) {
    const int p = t & 1, q = 1 - p;
    // layer 0: x_t -> h0
    gru_cell<<<32, 256, 0, stream>>>(
        x_bf + (size_t)t * I_, (long)S_ * I_, I_,
        wih0_bf, whh0_bf,
        h0b + p * HSZ, h0f + p * HSZ,
        b_ih0, b_hh0,
        h0f + q * HSZ, h0b + q * HSZ,
        (u16*)nullptr, 0);
    // layer 1: h0_t -> h1, also emit Y[:, t, :]
    gru_cell<<<32, 256, 0, stream>>>(
        h0b + q * HSZ, (long)H_, H_,
        wih1_bf, whh1_bf,
        h1b + p * HSZ, h1f + p * HSZ,
        b_ih1, b_hh1,
        h1f + q * HSZ, h1b + q * HSZ,
        y_bf + (size_t)t * H_, (long)S_ * H_);
  }

  // logits = Y @ Wfc^T + b_fc   (M=65536, N=512, K=512)
  fc_gemm<<<2048, 256, 0, stream>>>(y_bf, wfc_bf, b_fc, out);

  // hidden = stack([h0_final, h1_final]); final states land in slot 0 (t=1023 writes q=0)
  copy_hidden<<<128, 256, 0, stream>>>(h0f, h1f, out + (size_t)B_ * S_ * O_);
}

// Round 2
// 11897.488 us; speedup vs baseline: 3.1088x; 3.1088x over previous
//
#include <hip/hip_runtime.h>

// GRU 2-layer persistent-kernel design (Round 2).
// B=64, S=1024, I=256, H=512, O=512.
// - ONE persistent kernel runs the whole 1024-step recurrence.
// - 64 blocks x 256 threads (1 block/CU, trivially co-resident).
// - blocks 0..31: layer0 (16 hidden units each); 32..63: layer1.
// - wavefront pipelining: layer0 does step i while layer1 does step i-1
//   => ONE device-scope grid barrier per step (1025 total).
// - weights held as bf16 MFMA B-fragments in REGISTERS (loaded once from f32).
// - A-fragments straight from L2 (ping-pong bf16 h buffers, pre-converted x).
// - 4 waves k-split; cross-wave reduce + gate math via LDS; fp32 h state in LDS.

typedef unsigned short u16;
typedef __attribute__((ext_vector_type(8))) short bf16x8;
typedef __attribute__((ext_vector_type(4))) float f32x4;

#define B_ 64
#define S_ 1024
#define I_ 256
#define H_ 512
#define O_ 512
#define NBLK 64

#define MFMA_(a, b, c) __builtin_amdgcn_mfma_f32_16x16x32_bf16((a), (b), (c), 0, 0, 0)

__device__ __forceinline__ u16 f2bf(float f) {
  union { float f; unsigned u; } v; v.f = f;
  unsigned r = v.u + 0x7fffu + ((v.u >> 16) & 1u);  // RNE
  return (u16)(r >> 16);
}

__device__ __forceinline__ float sigmoidf_(float x) {
  return 1.0f / (1.0f + __expf(-x));
}

struct Bar { unsigned cnt; unsigned pad0[31]; unsigned gen; unsigned pad1[31]; };

// Generation-counter grid barrier (monotonic target; device scope).
__device__ __forceinline__ void grid_bar(Bar* bar, unsigned target) {
  __syncthreads();
  if (threadIdx.x == 0) {
    __threadfence();  // release: publish h writes device-wide
    unsigned old = __hip_atomic_fetch_add(&bar->cnt, 1u, __ATOMIC_ACQ_REL,
                                          __HIP_MEMORY_SCOPE_AGENT);
    if (old == (unsigned)(NBLK - 1)) {
      __hip_atomic_store(&bar->cnt, 0u, __ATOMIC_RELAXED, __HIP_MEMORY_SCOPE_AGENT);
      __hip_atomic_fetch_add(&bar->gen, 1u, __ATOMIC_RELEASE, __HIP_MEMORY_SCOPE_AGENT);
    } else {
      unsigned g;
      do {
        g = __hip_atomic_load(&bar->gen, __ATOMIC_ACQUIRE, __HIP_MEMORY_SCOPE_AGENT);
        if (g < target) __builtin_amdgcn_s_sleep(1);
      } while (g < target);
    }
    __threadfence();  // acquire side
  }
  __syncthreads();
}

// One layer's persistent loop. NK = K/(32*4) per wave. LAYER selects routing.
// xin: LAYER0 -> x_bf [t][b][c]; LAYER1 -> h0 ping-pong base.
template<int NK, int LAYER>
__device__ void layer_run(
    const u16* __restrict__ xin,
    const float* __restrict__ Wih, const float* __restrict__ Whh,
    const float* __restrict__ bih, const float* __restrict__ bhh,
    u16* __restrict__ hself,            // ping-pong [2][64*512] bf16
    u16* __restrict__ ybf,              // LAYER1: [b][t][u] bf16
    float* __restrict__ outh,           // final hidden f32 [64*512]
    float (*dump)[4][4][256], float* hst, float (*bias_s)[16], Bar* bar)
{
  const int tid = threadIdx.x;
  const int wave = tid >> 6, lane = tid & 63, lm = lane & 15, quad = lane >> 4;
  const int U0 = (blockIdx.x & 31) << 4;       // this block's 16 hidden units
  const int Kx = (LAYER == 0) ? I_ : H_;       // boundary between gi and gh input
  const int KW = NK * 32;                      // K-slice per wave
  const int wbase = wave * KW;

  if (tid < 16) {
    bias_s[0][tid] = bih[U0 + tid] + bhh[U0 + tid];                  // r
    bias_s[1][tid] = bih[H_ + U0 + tid] + bhh[H_ + U0 + tid];        // z
    bias_s[2][tid] = bih[2 * H_ + U0 + tid];                         // n (x part)
    bias_s[3][tid] = bhh[2 * H_ + U0 + tid];                         // n (h part)
  }
  #pragma unroll
  for (int j = 0; j < 4; ++j) hst[tid + j * 256] = 0.f;

  // ---- load B fragments once: f32 weights -> bf16 regs ----
  bf16x8 Bfr[3][NK];
  int aoffb[NK], astr16[NK];
  bool insel[NK], isx[NK];
  #pragma unroll
  for (int ks = 0; ks < NK; ++ks) {
    const int kb = wbase + ks * 32;
    const bool xr = (kb < Kx);
    insel[ks] = xr; isx[ks] = xr;
    const int col = (xr ? kb : kb - Kx) + quad * 8;
    const int stride = xr ? ((LAYER == 0) ? I_ : H_) : H_;
    aoffb[ks] = lm * stride + col;
    astr16[ks] = stride << 4;
    #pragma unroll
    for (int g = 0; g < 3; ++g) {
      const int row = g * H_ + U0 + lm;
      const float* src = xr ? (Wih + (size_t)row * Kx + kb + quad * 8)
                            : (Whh + (size_t)row * H_ + (kb - Kx) + quad * 8);
      float4 lo = *(const float4*)src;
      float4 hi = *(const float4*)(src + 4);
      bf16x8 v;
      v[0] = (short)f2bf(lo.x); v[1] = (short)f2bf(lo.y);
      v[2] = (short)f2bf(lo.z); v[3] = (short)f2bf(lo.w);
      v[4] = (short)f2bf(hi.x); v[5] = (short)f2bf(hi.y);
      v[6] = (short)f2bf(hi.z); v[7] = (short)f2bf(hi.w);
      Bfr[g][ks] = v;
    }
  }
  __syncthreads();

  // ---- time loop: 1025 barrier intervals ----
  for (unsigned i = 0; i <= S_; ++i) {
    const bool active = (LAYER == 0) ? (i < S_) : (i >= 1);
    if (active) {
      const int t = (LAYER == 0) ? (int)i : (int)i - 1;
      const u16* ain = (LAYER == 0) ? (xin + (size_t)t * (B_ * I_))
                                    : (xin + (size_t)(t & 1) * (B_ * H_));
      const u16* aself = hself + (size_t)((t - 1) & 1) * (B_ * H_);

      f32x4 aR[4] = {}, aZ[4] = {}, aNx[4] = {}, aNh[4] = {};
      #pragma unroll
      for (int ks = 0; ks < NK; ++ks) {
        const u16* p = (insel[ks] ? ain : aself) + aoffb[ks];
        bf16x8 A0 = *(const bf16x8*)(p);
        bf16x8 A1 = *(const bf16x8*)(p + astr16[ks]);
        bf16x8 A2 = *(const bf16x8*)(p + 2 * astr16[ks]);
        bf16x8 A3 = *(const bf16x8*)(p + 3 * astr16[ks]);
        aR[0] = MFMA_(A0, Bfr[0][ks], aR[0]);
        aR[1] = MFMA_(A1, Bfr[0][ks], aR[1]);
        aR[2] = MFMA_(A2, Bfr[0][ks], aR[2]);
        aR[3] = MFMA_(A3, Bfr[0][ks], aR[3]);
        aZ[0] = MFMA_(A0, Bfr[1][ks], aZ[0]);
        aZ[1] = MFMA_(A1, Bfr[1][ks], aZ[1]);
        aZ[2] = MFMA_(A2, Bfr[1][ks], aZ[2]);
        aZ[3] = MFMA_(A3, Bfr[1][ks], aZ[3]);
        if (isx[ks]) {
          aNx[0] = MFMA_(A0, Bfr[2][ks], aNx[0]);
          aNx[1] = MFMA_(A1, Bfr[2][ks], aNx[1]);
          aNx[2] = MFMA_(A2, Bfr[2][ks], aNx[2]);
          aNx[3] = MFMA_(A3, Bfr[2][ks], aNx[3]);
        } else {
          aNh[0] = MFMA_(A0, Bfr[2][ks], aNh[0]);
          aNh[1] = MFMA_(A1, Bfr[2][ks], aNh[1]);
          aNh[2] = MFMA_(A2, Bfr[2][ks], aNh[2]);
          aNh[3] = MFMA_(A3, Bfr[2][ks], aNh[3]);
        }
      }

      // dump partials to LDS
      #pragma unroll
      for (int mt = 0; mt < 4; ++mt) {
        *(f32x4*)&dump[wave][0][mt][lane << 2] = aR[mt];
        *(f32x4*)&dump[wave][1][mt][lane << 2] = aZ[mt];
        *(f32x4*)&dump[wave][2][mt][lane << 2] = aNx[mt];
        *(f32x4*)&dump[wave][3][mt][lane << 2] = aNh[mt];
      }
      __syncthreads();

      // reduce + gate math + publish (4 h-values per thread)
      u16* hpub = hself + (size_t)(t & 1) * (B_ * H_);
      #pragma unroll
      for (int j = 0; j < 4; ++j) {
        const int v = tid + (j << 8);
        const int m = v >> 4, u = v & 15;
        const int mt = m >> 4;
        const int ln = ((m & 12) << 2) | u;    // quad(m)*16 + u
        const int idx = (ln << 2) | (m & 3);
        float r = 0.f, z = 0.f, nx = 0.f, nh = 0.f;
        #pragma unroll
        for (int w = 0; w < 4; ++w) {
          r  += dump[w][0][mt][idx];
          z  += dump[w][1][mt][idx];
          nx += dump[w][2][mt][idx];
          nh += dump[w][3][mt][idx];
        }
        r = sigmoidf_(r + bias_s[0][u]);
        z = sigmoidf_(z + bias_s[1][u]);
        const float nn = tanhf(nx + bias_s[2][u] + r * (nh + bias_s[3][u]));
        const float hp = hst[(m << 4) | u];
        const float hn = (1.f - z) * nn + z * hp;
        hst[(m << 4) | u] = hn;
        const u16 hb = f2bf(hn);
        hpub[m * H_ + U0 + u] = hb;
        if (LAYER == 1) ybf[((size_t)m * S_ + t) * H_ + U0 + u] = hb;
        if (t == S_ - 1) outh[m * H_ + U0 + u] = hn;
      }
    }
    grid_bar(bar, i + 1);
  }
}

__global__ __launch_bounds__(256, 1) void gru_persistent(
    const u16* __restrict__ x_bf,
    const float* __restrict__ Wih0, const float* __restrict__ Whh0,
    const float* __restrict__ bih0, const float* __restrict__ bhh0,
    const float* __restrict__ Wih1, const float* __restrict__ Whh1,
    const float* __restrict__ bih1, const float* __restrict__ bhh1,
    u16* __restrict__ h0buf, u16* __restrict__ h1buf,
    u16* __restrict__ ybf, float* __restrict__ outh, Bar* bar)
{
  __shared__ float dump[4][4][4][256];   // 64 KB
  __shared__ float hst[1024];            // 4 KB fp32 h state (this block's slice)
  __shared__ float bias_s[4][16];
  if (blockIdx.x < 32)
    layer_run<6, 0>(x_bf, Wih0, Whh0, bih0, bhh0, h0buf, (u16*)nullptr,
                    outh, dump, hst, bias_s, bar);
  else
    layer_run<8, 1>(h0buf, Wih1, Whh1, bih1, bhh1, h1buf, ybf,
                    outh + B_ * H_, dump, hst, bias_s, bar);
}

// ---------------- x transpose+convert: [b][t][c] f32 -> [t][b][c] bf16 ----------------
__global__ void conv_x(const float* __restrict__ src, u16* __restrict__ dst) {
  const int idx = blockIdx.x * 256 + threadIdx.x;   // 64*1024*64 quads
  const int c4 = idx & 63, tt = (idx >> 6) & 1023, b = idx >> 16;
  float4 v = *(const float4*)(src + (((size_t)(b << 10) | tt) << 8) + (c4 << 2));
  ushort4 o;
  o.x = f2bf(v.x); o.y = f2bf(v.y); o.z = f2bf(v.z); o.w = f2bf(v.w);
  *(ushort4*)(dst + (((size_t)(tt << 6) | b) << 8) + (c4 << 2)) = o;
}

// ---------------- generic f32 -> bf16 ----------------
__global__ void conv_bf16(const float* __restrict__ src, u16* __restrict__ dst, int n4) {
  int i = blockIdx.x * blockDim.x + threadIdx.x;
  int stride = gridDim.x * blockDim.x;
  for (; i < n4; i += stride) {
    float4 v = ((const float4*)src)[i];
    ushort4 o;
    o.x = f2bf(v.x); o.y = f2bf(v.y); o.z = f2bf(v.z); o.w = f2bf(v.w);
    ((ushort4*)dst)[i] = o;
  }
}

// ---------------- final FC: C[65536,512] = Y @ Wfc^T + b (verified R1) ----------------
__global__ __launch_bounds__(256) void fc_gemm(
    const u16* __restrict__ A, const u16* __restrict__ Bm,
    const float* __restrict__ bias, float* __restrict__ C)
{
  const int bid = blockIdx.x;
  const int bm = bid >> 2, bn = bid & 3;
  const int wave = threadIdx.x >> 6, lane = threadIdx.x & 63;
  const int wm = wave >> 1, wn = wave & 1;
  const int M0 = bm * 128 + wm * 64;
  const int N0 = bn * 128 + wn * 64;
  const int lm = lane & 15, quad = lane >> 4;

  f32x4 acc[4][4];
  #pragma unroll
  for (int j = 0; j < 4; ++j) {
    float bv = bias[N0 + j * 16 + lm];
    #pragma unroll
    for (int i = 0; i < 4; ++i) acc[i][j] = (f32x4){bv, bv, bv, bv};
  }

  const u16* a0 = A + (size_t)(M0 + lm) * 512 + quad * 8;
  const u16* b0 = Bm + (size_t)(N0 + lm) * 512 + quad * 8;
  for (int ks = 0; ks < 512; ks += 32) {
    bf16x8 af[4], bfr[4];
    #pragma unroll
    for (int i = 0; i < 4; ++i) af[i]  = *(const bf16x8*)(a0 + (size_t)i * 16 * 512 + ks);
    #pragma unroll
    for (int j = 0; j < 4; ++j) bfr[j] = *(const bf16x8*)(b0 + (size_t)j * 16 * 512 + ks);
    #pragma unroll
    for (int i = 0; i < 4; ++i)
      #pragma unroll
      for (int j = 0; j < 4; ++j)
        acc[i][j] = MFMA_(af[i], bfr[j], acc[i][j]);
  }

  #pragma unroll
  for (int i = 0; i < 4; ++i)
    #pragma unroll
    for (int j = 0; j < 4; ++j)
      #pragma unroll
      for (int r = 0; r < 4; ++r) {
        const int m = M0 + i * 16 + quad * 4 + r;
        const int n = N0 + j * 16 + lm;
        C[(size_t)m * 512 + n] = acc[i][j][r];
      }
}

// ---------------- host ----------------
extern "C" void kernel_launch(void* const* d_in, const int* in_sizes, int n_in,
                              void* d_out, int out_size, void* d_ws, size_t ws_size,
                              hipStream_t stream) {
  const float* x     = (const float*)d_in[0];
  const float* W_ih0 = (const float*)d_in[1];
  const float* W_hh0 = (const float*)d_in[2];
  const float* b_ih0 = (const float*)d_in[3];
  const float* b_hh0 = (const float*)d_in[4];
  const float* W_ih1 = (const float*)d_in[5];
  const float* W_hh1 = (const float*)d_in[6];
  const float* b_ih1 = (const float*)d_in[7];
  const float* b_hh1 = (const float*)d_in[8];
  const float* W_fc  = (const float*)d_in[9];
  const float* b_fc  = (const float*)d_in[10];
  float* out = (float*)d_out;

  char* ws = (char*)d_ws;
  const size_t OFF_XBF = 0;               // [1024][64][256] bf16 = 33,554,432
  const size_t OFF_YBF = 33554432;        // [64][1024][512] bf16 = 67,108,864
  const size_t OFF_WFC = 100663296;       // 512*512 bf16 = 524,288
  const size_t OFF_H0  = 101187584;       // 2 * 64*512 bf16 = 131,072
  const size_t OFF_H1  = 101318656;       // 131,072
  const size_t OFF_BAR = 101449728;       // 256

  u16* x_bf   = (u16*)(ws + OFF_XBF);
  u16* y_bf   = (u16*)(ws + OFF_YBF);
  u16* wfc_bf = (u16*)(ws + OFF_WFC);
  u16* h0buf  = (u16*)(ws + OFF_H0);
  u16* h1buf  = (u16*)(ws + OFF_H1);
  Bar* bar    = (Bar*)(ws + OFF_BAR);

  // zero h ping-pong buffers + barrier state (contiguous)
  hipMemsetAsync(ws + OFF_H0, 0, 131072 * 2 + 256, stream);

  // x: transpose+convert; W_fc: convert
  conv_x<<<16384, 256, 0, stream>>>(x, x_bf);
  conv_bf16<<<256, 256, 0, stream>>>(W_fc, wfc_bf, (O_ * H_) / 4);

  // whole recurrence in one persistent kernel
  gru_persistent<<<NBLK, 256, 0, stream>>>(
      x_bf, W_ih0, W_hh0, b_ih0, b_hh0, W_ih1, W_hh1, b_ih1, b_hh1,
      h0buf, h1buf, y_bf, out + (size_t)B_ * S_ * O_, bar);

  // logits = Y @ Wfc^T + b_fc
  fc_gemm<<<2048, 256, 0, stream>>>(y_bf, wfc_bf, b_fc, out);
}